// Round 14
// baseline (455.141 us; speedup 1.0000x reference)
//
#include <hip/hip_runtime.h>

// CRF Viterbi decode (B=512, T=512, S=64).
// R13: 2 waves per batch -- the only shape that puts a wave on ALL 1024
// SIMDs (512 blocks x 128 thr). Single-wave/batch leaves half the machine
// idle (R12: occ 5.9%, 1625 cyc/step); 4/8-wave shapes pay ~700 cyc of
// barrier+LDS exposure (R3/R9/R11 plateau ~1330 cyc/step). Here: cheapest
// rendezvous (2 waves), halved per-wave issue vs R12.
// Wave w owns prev half [32w,32w+32); lane n carries tag tg = n ^ 32w
// (xor space, validated R8/R9) so the slice is LITERAL lanes 0..31 of its
// own fv copy -> v_readlane never waterfalls (R6's failure mode fixed).
// Per step: 32 rl+add, 31-node carry-index ordered tree (strict >,
// left-on-tie = exact jnp first-argmax), SoA b32 partial write, ONE
// lgkmcnt-only barrier (prefetch loads stay in flight, validated R9),
// partner b32 read (permutation addressing, conflict-free), one ordered
// merge (wave0 half = left operand), fma. Emissions/masks prefetched in
// groups of 4, 2 groups deep (validated R9). Backpointers packed 4
// tags/dword by wave 0 (identity space); backtrace = validated readlane
// chain. Output: out[0..B) = path_score, out[B + b*(T-1) + t] = (float)tag.

constexpr int Bz = 512;
constexpr int Tz = 512;
constexpr int Sz = 64;
constexpr float NEGINF = -10000.0f;

__device__ __forceinline__ float rlf(float x, int lane) {
    return __int_as_float(__builtin_amdgcn_readlane(__float_as_int(x), lane));
}

// Barrier waiting only on LDS ops (lgkmcnt), not vmcnt: prefetch global
// loads stay in flight across the rendezvous. (Validated R9-R11.)
__device__ __forceinline__ void lds_barrier() {
    asm volatile("s_waitcnt lgkmcnt(0)\n\ts_barrier" ::: "memory");
}

__global__ __launch_bounds__(128)
void crf_viterbi_kernel(const float* __restrict__ logits,
                        const float* __restrict__ masks,
                        const float* __restrict__ trans,
                        float* __restrict__ out)
{
    const int n  = threadIdx.x & 63;                                  // lane id
    const int w  = __builtin_amdgcn_readfirstlane(threadIdx.x >> 6);  // 0 or 1
    const int b  = blockIdx.x;
    const int pb = 32 * w;            // first prev of this wave's half
    const int tg = n ^ pb;            // this lane's tag in wave-w swapped space

    __shared__ unsigned bp[128 * 64];   // packed backpointers, 32 KB
    __shared__ float pval[2][2][64];    // [buf][wave][tag] partial value
    __shared__ int   pidx[2][2][64];    // [buf][wave][tag] partial argmax
    __shared__ float ys[Tz - 1];        // emitted tags (backtrace)

    // transitions slice: tr[j] = trans[tg][pb + j], j = 0..31
    float tr[32];
    {
        const float4* tr4 = reinterpret_cast<const float4*>(trans + tg * 64 + pb);
        #pragma unroll
        for (int k = 0; k < 8; ++k) {
            float4 t = tr4[k];
            tr[4 * k + 0] = t.x; tr[4 * k + 1] = t.y;
            tr[4 * k + 2] = t.z; tr[4 * k + 3] = t.w;
        }
    }

    // fv in swapped layout: lane n holds fv[tg]
    float fv = (tg == 0) ? 0.0f : NEGINF;

    const float* lgbase = logits + (size_t)b * Tz * Sz;
    const float* mkbase = masks + (size_t)b * Tz;

    // group-of-4 prefetch, 2 groups deep (validated R9 scheme)
    float lgc[4], lgn[4], mkc[4], mkn[4];
    #pragma unroll
    for (int k = 0; k < 4; ++k) {
        lgc[k] = lgbase[(1 + k) * Sz + tg];  mkc[k] = mkbase[1 + k];
        lgn[k] = lgbase[(5 + k) * Sz + tg];  mkn[k] = mkbase[5 + k];
    }

    unsigned pk = 0;
    float psc = 0.0f;

    // one Viterbi step; k compile-time => literal buf parity, literal lanes
    auto step = [&](int k, float lg, float mk) -> float {
        const int buf = k & 1;
        // 32 literal-lane gathers + adds, first tree level fused (16 nodes)
        float mv[16]; int mi[16];
        #pragma unroll
        for (int c = 0; c < 16; ++c) {
            float va = rlf(fv, 2 * c)     + tr[2 * c];
            float vb = rlf(fv, 2 * c + 1) + tr[2 * c + 1];
            bool g = vb > va;
            mv[c] = g ? vb : va;
            mi[c] = g ? (pb + 2 * c + 1) : (pb + 2 * c);
        }
        // balanced carry-index merge, depth 4 (strict >, left keeps ties)
        #pragma unroll
        for (int st = 1; st < 16; st <<= 1) {
            #pragma unroll
            for (int c = 0; c < 16; c += 2 * st) {
                bool g = mv[c + st] > mv[c];
                mv[c] = g ? mv[c + st] : mv[c];
                mi[c] = g ? mi[c + st] : mi[c];
            }
        }

        pval[buf][w][tg] = mv[0];
        pidx[buf][w][tg] = pb + 0 * 0 + mi[0] - 0;   // global prev already in mi? no:
        // mi[] already carries pb -> store directly
        pidx[buf][w][tg] = mi[0];

        lds_barrier();                   // the ONLY barrier per step

        float ov = pval[buf][1 - w][tg];
        int   oi = pidx[buf][1 - w][tg];

        // ordered merge: prevs [0,32) (wave 0's half) is the LEFT operand
        float lv = (w == 0) ? mv[0] : ov;
        int   li = (w == 0) ? mi[0] : oi;
        float rv = (w == 0) ? ov    : mv[0];
        int   ri = (w == 0) ? oi    : mi[0];
        bool g = rv > lv;
        float m  = g ? rv : lv;
        int   gi = g ? ri : li;

        pk |= ((unsigned)gi) << (8 * k);     // wave0: tg==n (identity space)
        fv = m + lg * mk;                    // mask multiplies emission only
        return m;                            // pre-feat max (path_score)
    };

    // main: groups g = 0..126 cover steps i = 4g+k (i <= 507)
    for (int g = 0; g < 127; ++g) {
        step(0, lgc[0], mkc[0]);
        step(1, lgc[1], mkc[1]);
        step(2, lgc[2], mkc[2]);
        step(3, lgc[3], mkc[3]);

        if (w == 0) bp[g * 64 + n] = pk;     // identity space in wave 0
        pk = 0;

        // rotate prefetch; issue loads for group g+2 (rows 4g+9 .. 4g+12)
        #pragma unroll
        for (int k = 0; k < 4; ++k) { lgc[k] = lgn[k]; mkc[k] = mkn[k]; }
        #pragma unroll
        for (int k = 0; k < 4; ++k) {
            int t = 4 * g + 9 + k;
            t = (t < Tz) ? t : (Tz - 1);
            lgn[k] = lgbase[t * Sz + tg];
            mkn[k] = mkbase[t];
        }
    }

    // tail: steps 508 (k0), 509 (k1), 510 (k2); i = 510 == Tz-2 -> path_score
    step(0, lgc[0], mkc[0]);
    step(1, lgc[1], mkc[1]);
    psc = step(2, lgc[2], mkc[2]);           // vmaxs[-1] pre-feat

    if (w == 0) {
        bp[127 * 64 + n] = pk;               // flush steps 508..510
        if (n == 63) out[b] = psc;           // path_score = vmaxs[-1][:,63]
    }
    __syncthreads();

    // ---- backtrace (wave 0 only; validated readlane chain) ----
    if (w == 0) {
        unsigned wcur = bp[127 * 64 + n];
        int w127_63 = __builtin_amdgcn_readlane((int)wcur, 63);
        int tag = (w127_63 >> 16) & 255;     // t0 = bptrs[510][63]

        for (int g = 127; g >= 0; --g) {
            unsigned wnext = (g > 0) ? bp[(g - 1) * 64 + n] : 0u;  // prefetch
            int smax = (g == 127) ? 2 : 3;
            for (int s = smax; s >= 0; --s) {
                int idx = 4 * g + s;
                if (n == 0) ys[idx] = (float)tag;   // emit BEFORE following ptr
                int wd = __builtin_amdgcn_readlane((int)wcur, tag);
                tag = (wd >> (8 * s)) & 255;
            }
            wcur = wnext;
        }
    }
    __syncthreads();

    float* outseq = out + Bz + (size_t)b * (Tz - 1);
    for (int k = threadIdx.x; k < Tz - 1; k += 128) outseq[k] = ys[k];
}

extern "C" void kernel_launch(void* const* d_in, const int* in_sizes, int n_in,
                              void* d_out, int out_size, void* d_ws, size_t ws_size,
                              hipStream_t stream) {
    const float* logits = (const float*)d_in[0];
    const float* masks  = (const float*)d_in[1];
    const float* trans  = (const float*)d_in[2];
    float* out = (float*)d_out;
    (void)in_sizes; (void)n_in; (void)out_size; (void)d_ws; (void)ws_size;

    crf_viterbi_kernel<<<dim3(Bz), dim3(128), 0, stream>>>(logits, masks, trans, out);
}

// Round 15
// 397.030 us; speedup vs baseline: 1.1464x; 1.1464x over previous
//
#include <hip/hip_runtime.h>

// CRF Viterbi decode (B=512, T=512, S=64).
// R14: TWO-PASS. Single wave per batch (512 x 64), barrier-free.
// Pass 1 (forward, values only): fv recursion WITHOUT argmax -- 64
// literal-lane readlanes (validated R1/R12: never waterfalls) + 64 adds +
// 63-fmax balanced tree (exact max; compiler folds to v_max3). Each fv_i
// (the vector ENTERING step i) is stored as one coalesced 256 B row to
// scratch: d_ws if ws_size suffices, else in-place into logits row i
// (row i is fully consumed before fv_i exists; row 0 is never read).
// This deletes the ~190 instr/step of index-carry that bounded R12.
// Pass 2 (backward): the backtrace needs only ONE backpointer per step:
// bptr_i[tag] = first-argmax_p(fv_i[p] + trans[tag][p]). Recomputed
// bit-exactly (same add, max is exactly associative), lane p = prev:
// trans row from LDS (2-way bank alias = free), DPP wave-max
// (row_shr:1/2/4/8 + row_bcast:15/31 -> lane 63), readlane broadcast,
// equality -> candidate lane index (64 if not achiever), DPP wave-min ->
// smallest achieving prev == jnp.argmax first-max semantics, exact.
// Seed = bptr_510[63]; walk re-applies row 510 (torch quirk, validated).
// Output: out[0..B) = path_score, out[B + b*(T-1) + t] = (float)tag.

constexpr int Bz = 512;
constexpr int Tz = 512;
constexpr int Sz = 64;
constexpr float NEGINF = -10000.0f;

__device__ __forceinline__ float rlf(float x, int lane) {
    return __int_as_float(__builtin_amdgcn_readlane(__float_as_int(x), lane));
}

template <int C>
__device__ __forceinline__ float dppmaxf(float x) {
    int t = __builtin_amdgcn_update_dpp(__float_as_int(x), __float_as_int(x),
                                        C, 0xf, 0xf, false);
    return fmaxf(x, __int_as_float(t));
}
template <int C>
__device__ __forceinline__ int dppmini(int x) {
    int t = __builtin_amdgcn_update_dpp(x, x, C, 0xf, 0xf, false);
    return (t < x) ? t : x;
}

// Wave-wide exact max, broadcast to all lanes via readlane(63).
__device__ __forceinline__ float wave_max_bcast(float x) {
    x = dppmaxf<0x111>(x);   // row_shr:1
    x = dppmaxf<0x112>(x);   // row_shr:2
    x = dppmaxf<0x114>(x);   // row_shr:4
    x = dppmaxf<0x118>(x);   // row_shr:8
    x = dppmaxf<0x142>(x);   // row_bcast:15
    x = dppmaxf<0x143>(x);   // row_bcast:31 -> lane 63 = full max
    return rlf(x, 63);
}
// Wave-wide min of ints (lane-index candidates), result via readlane(63).
__device__ __forceinline__ int wave_min_bcast(int x) {
    x = dppmini<0x111>(x);
    x = dppmini<0x112>(x);
    x = dppmini<0x114>(x);
    x = dppmini<0x118>(x);
    x = dppmini<0x142>(x);
    x = dppmini<0x143>(x);
    return __builtin_amdgcn_readlane(x, 63);
}

__global__ __launch_bounds__(64)
void crf_viterbi_kernel(const float* __restrict__ logits,
                        const float* __restrict__ masks,
                        const float* __restrict__ trans,
                        float* __restrict__ out,
                        float* __restrict__ fvst)   // may alias logits
{
    const int n = threadIdx.x & 63;   // lane id: tag (fwd) / prev (bwd)
    const int b = blockIdx.x;

    __shared__ float ltr[64 * 64];    // transitions, 16 KB
    __shared__ float ys[Tz - 1];      // emitted tags (backtrace)

    // stage transitions into LDS (single wave: no barrier needed; also
    // needed in registers for the forward pass)
    float tr[64];
    {
        const float4* tr4 = reinterpret_cast<const float4*>(trans + n * 64);
        #pragma unroll
        for (int k = 0; k < 16; ++k) {
            float4 t = tr4[k];
            tr[4 * k + 0] = t.x; tr[4 * k + 1] = t.y;
            tr[4 * k + 2] = t.z; tr[4 * k + 3] = t.w;
        }
        for (int r = 0; r < 64; ++r) ltr[r * 64 + n] = trans[r * 64 + n];
    }

    float fv = (n == 0) ? 0.0f : NEGINF;

    const float* lgbase = logits + (size_t)b * Tz * Sz;
    const float* mkbase = masks + (size_t)b * Tz;
    float* fvb = fvst + (size_t)b * Tz * Sz;   // fv_i at row i (+ lane n)

    // group-of-4 prefetch, 2 groups deep (validated R9/R12 scheme)
    float lgc[4], lgn[4], mkc[4], mkn[4];
    #pragma unroll
    for (int k = 0; k < 4; ++k) {
        lgc[k] = lgbase[(1 + k) * Sz + n];  mkc[k] = mkbase[1 + k];
        lgn[k] = lgbase[(5 + k) * Sz + n];  mkn[k] = mkbase[5 + k];
    }

    float psc = 0.0f;

    // ---- forward step: store fv_i, value-only max, update ----
    auto fstep = [&](int i, float lg, float mk) -> float {
        fvb[i * Sz + n] = fv;                    // row i is already consumed
        float v[64];
        #pragma unroll
        for (int j = 0; j < 64; ++j)
            v[j] = rlf(fv, j) + tr[j];
        #pragma unroll
        for (int st = 1; st < 64; st <<= 1) {
            #pragma unroll
            for (int c = 0; c < 64; c += 2 * st)
                v[c] = fmaxf(v[c], v[c + st]);   // exact max, any shape
        }
        float m = v[0];
        fv = m + lg * mk;                        // mask multiplies emission only
        return m;                                // pre-feat max
    };

    // main: groups g = 0..126 cover steps i = 4g+k (i <= 507)
    for (int g = 0; g < 127; ++g) {
        int i0 = 4 * g;
        fstep(i0 + 0, lgc[0], mkc[0]);
        fstep(i0 + 1, lgc[1], mkc[1]);
        fstep(i0 + 2, lgc[2], mkc[2]);
        fstep(i0 + 3, lgc[3], mkc[3]);

        #pragma unroll
        for (int k = 0; k < 4; ++k) { lgc[k] = lgn[k]; mkc[k] = mkn[k]; }
        #pragma unroll
        for (int k = 0; k < 4; ++k) {
            int t = 4 * g + 9 + k;
            t = (t < Tz) ? t : (Tz - 1);
            lgn[k] = lgbase[t * Sz + n];
            mkn[k] = mkbase[t];
        }
    }
    // tail: steps 508, 509, 510; i = 510 == Tz-2 -> path_score
    fstep(508, lgc[0], mkc[0]);
    fstep(509, lgc[1], mkc[1]);
    psc = fstep(510, lgc[2], mkc[2]);            // vmaxs[-1] pre-feat

    if (n == 63) out[b] = psc;                   // path_score = vmaxs[-1][:,63]

    // ---- backward: one argmax per step, DPP reduces ----
    // bptr(frow, tag) = smallest p maximizing frow[p] + trans[tag][p]
    auto bstep = [&](float frow, int tg) -> int {
        float val = frow + ltr[tg * 64 + n];     // lane p = prev
        float m = wave_max_bcast(val);           // exact max (same adds as fwd)
        int cand = (val == m) ? n : 64;
        return wave_min_bcast(cand);             // first achiever (smallest p)
    };

    // sliding window of fv rows, prefetched (row order known: 510..0)
    float fw0 = fvb[510 * Sz + n];
    float fw1 = fvb[509 * Sz + n];
    float fw2 = fvb[508 * Sz + n];
    float fw3 = fvb[507 * Sz + n];

    int tag = bstep(fw0, 63);                    // seed = bptrs[510][63]
    for (int i = 510; i >= 0; --i) {
        if (n == 0) ys[i] = (float)tag;          // emit BEFORE following ptr
        tag = bstep(fw0, tag);                   // row 510 re-applied first
        fw0 = fw1; fw1 = fw2; fw2 = fw3;
        int r = i - 4; r = (r < 0) ? 0 : r;
        fw3 = fvb[r * Sz + n];
    }

    __syncthreads();
    float* outseq = out + Bz + (size_t)b * (Tz - 1);
    for (int k = n; k < Tz - 1; k += 64) outseq[k] = ys[k];
}

extern "C" void kernel_launch(void* const* d_in, const int* in_sizes, int n_in,
                              void* d_out, int out_size, void* d_ws, size_t ws_size,
                              hipStream_t stream) {
    const float* logits = (const float*)d_in[0];
    const float* masks  = (const float*)d_in[1];
    const float* trans  = (const float*)d_in[2];
    float* out = (float*)d_out;
    (void)in_sizes; (void)n_in; (void)out_size;

    // fv history: 512*512*64*4 = 67,108,864 B. Use d_ws if it fits, else
    // write in-place into logits rows already consumed (restored by the
    // harness from a pristine copy before every launch).
    const size_t need = (size_t)Bz * Tz * Sz * sizeof(float);
    float* fvst = (ws_size >= need) ? (float*)d_ws : (float*)d_in[0];

    crf_viterbi_kernel<<<dim3(Bz), dim3(64), 0, stream>>>(logits, masks, trans,
                                                          out, fvst);
}